// Round 4
// baseline (203.379 us; speedup 1.0000x reference)
//
#include <hip/hip_runtime.h>
#include <math.h>

#define TT 64

// wave-local LDS fence: waitcnt lgkmcnt(0) only (vmcnt untouched).
__device__ __forceinline__ void syncwave() {
    __builtin_amdgcn_wave_barrier();
    __builtin_amdgcn_s_waitcnt(0xC07F);   // vmcnt=63(no wait), expcnt=7, lgkmcnt=0
    __builtin_amdgcn_wave_barrier();
}

// DPP cross-lane adds (VALU pipe, ~4cyc — NOT the DS pipe).
// Reduction group = lane bits {0,1,3}: xor1/xor2 = quad_perm, xor-bit3 = row_ror:8.
#define DPP_XOR1 0xB1    // quad_perm [1,0,3,2]
#define DPP_XOR2 0x4E    // quad_perm [2,3,0,1]
#define DPP_XOR8 0x128   // row_ror:8  (swap halves of 16-row = lane ^ 8)

template<int CTRL>
__device__ __forceinline__ float dppx(float v) {
    return __int_as_float(__builtin_amdgcn_update_dpp(
        0, __float_as_int(v), CTRL, 0xF, 0xF, true));
}

// butterfly allreduce over the 8-lane group for 24 independent slots
__device__ __forceinline__ void allreduce24(float* A) {
    #pragma unroll
    for (int k = 0; k < 24; ++k) A[k] += dppx<DPP_XOR1>(A[k]);
    #pragma unroll
    for (int k = 0; k < 24; ++k) A[k] += dppx<DPP_XOR2>(A[k]);
    #pragma unroll
    for (int k = 0; k < 24; ++k) A[k] += dppx<DPP_XOR8>(A[k]);
}

// ---------------------------------------------------------------------------
// chains: block b = batch; wave 0 = question chain, wave 1 = answer chain.
// Lane mapping: i = lane bits {0,1,3} (row-group), j = bits {2,4,5} (column).
// State: up = Up[i][j] (own), uq[24] = full Uq column j (replicated, bitwise
// identical across the 8-group), xr[24] = row i of x (contiguous in memory).
// Step (same verified recurrence as R2/R3):
//   A = allreduce(xr*up) = s ; t_i = <xr, uq+A> ; C = allreduce(xr*t_i) = x^T t
//   up' = up - 2 t_i ; uq' = uq + 2A - 2C
// K-loop has ZERO DS instructions (all cross-lane via DPP), 6 VMEM loads/step.
// Wave 0 additionally builds yb = cayley(bias) in LDS (exact Gauss-Jordan)
// and applies U <- yb U at the end. dist^2 = 16 - 2||U0^T U1||_F^2.
// ---------------------------------------------------------------------------
__global__ __launch_bounds__(128, 1) void chains(
    const int* __restrict__ s1, const int* __restrict__ s2,
    const float* __restrict__ qemb, const float* __restrict__ aemb,
    const float* __restrict__ qtr, const float* __restrict__ qbias,
    const float* __restrict__ wf, const float* __restrict__ wb,
    float* __restrict__ out) {
    __shared__ float xb[192];
    __shared__ float Aug[8][16];
    __shared__ float Hm[192];
    __shared__ __align__(16) float ybs[1024];
    __shared__ __align__(16) float Ucm[2][8][32];   // [side][col][row]

    const int tid = threadIdx.x;
    const int s = tid >> 6;
    const int l = tid & 63;
    const int b = blockIdx.x;
    const int i = (l & 3) | ((l >> 1) & 4);          // bits {0,1,3}
    const int j = ((l >> 2) & 1) | ((l >> 3) & 6);   // bits {2,4,5}

    // ---- wave 0 prologue: yb via exact 8x8 Gauss-Jordan (wave-synchronous)
    if (s == 0) {
        xb[l] = qbias[l]; xb[l + 64] = qbias[l + 64]; xb[l + 128] = qbias[l + 128];
        syncwave();
        const int gi = l >> 3, gj = l & 7;
        float a = (gi == gj) ? 1.0f : 0.0f;
        for (int k = 0; k < 24; ++k) a += xb[gi * 24 + k] * xb[gj * 24 + k];
        Aug[gi][gj] = a;
        Aug[gi][gj + 8] = (gi == gj) ? 1.0f : 0.0f;
        syncwave();
        for (int k = 0; k < 8; ++k) {
            const float piv = Aug[k][k];
            syncwave();
            if (gi == k) {
                const float ip = 1.0f / piv;
                Aug[k][gj] *= ip;
                Aug[k][gj + 8] *= ip;
            }
            syncwave();
            const float f = Aug[gi][k];
            syncwave();
            if (gi != k) {
                Aug[gi][gj]     -= f * Aug[k][gj];
                Aug[gi][gj + 8] -= f * Aug[k][gj + 8];
            }
            syncwave();
        }
        for (int idx = l; idx < 192; idx += 64) {
            const int r = idx / 24, c = idx % 24;
            float h = 0.0f;
            for (int m = 0; m < 8; ++m) h += Aug[r][8 + m] * xb[m * 24 + c];
            Hm[idx] = h;
        }
        syncwave();
        for (int idx = l; idx < 1024; idx += 64) {
            const int r = idx >> 5, c = idx & 31;
            float v;
            if (r < 8 && c < 8) {
                v = 2.0f * Aug[r][8 + c] - ((r == c) ? 1.0f : 0.0f);
            } else if (r < 8) {
                v = -2.0f * Hm[r * 24 + (c - 8)];
            } else if (c < 8) {
                v = 2.0f * Hm[c * 24 + (r - 8)];
            } else {
                float s2 = 0.0f;
                for (int m = 0; m < 8; ++m) s2 += xb[m * 24 + (r - 8)] * Hm[m * 24 + (c - 8)];
                v = ((r == c) ? 1.0f : 0.0f) - 2.0f * s2;
            }
            ybs[idx] = v;
        }
        syncwave();
    }

    const int* sent = s ? s2 : s1;
    const float* emb = s ? aemb : qemb;
    const int myid = sent[b * TT + l];
    const bool qside = (s == 0);

    // transform row i (q-side), contiguous
    float trr[24];
    if (qside) {
        const float4* qr = (const float4*)(qtr + i * 24);
        #pragma unroll
        for (int u = 0; u < 6; ++u) {
            const float4 vv = qr[u];
            trr[4 * u + 0] = vv.x; trr[4 * u + 1] = vv.y;
            trr[4 * u + 2] = vv.z; trr[4 * u + 3] = vv.w;
        }
    }

    // state
    float up = (i == j) ? 1.0f : 0.0f;
    float uq[24];
    #pragma unroll
    for (int k = 0; k < 24; ++k) uq[k] = 0.0f;

    float xr[24];
    {   // load token TT-1 row i (contiguous: 6 float4)
        const int id = __shfl(myid, TT - 1);
        const float4* p = (const float4*)(emb + (size_t)id * 192 + i * 24);
        #pragma unroll
        for (int u = 0; u < 6; ++u) {
            const float4 vv = p[u];
            xr[4 * u + 0] = vv.x; xr[4 * u + 1] = vv.y;
            xr[4 * u + 2] = vv.z; xr[4 * u + 3] = vv.w;
        }
        if (qside) {
            #pragma unroll
            for (int k = 0; k < 24; ++k) xr[k] *= trr[k];
        }
    }

    #pragma unroll 1
    for (int t = TT - 1; t >= 0; --t) {
        // prefetch next token's row (consumed at bottom; stays in flight)
        float4 e[6];
        if (t > 0) {
            const int id2 = __shfl(myid, t - 1);
            const float4* p2 = (const float4*)(emb + (size_t)id2 * 192 + i * 24);
            #pragma unroll
            for (int u = 0; u < 6; ++u) e[u] = p2[u];
        }

        // A = s-slots: allreduce(xr[k] * up)
        float A[24];
        #pragma unroll
        for (int k = 0; k < 24; ++k) A[k] = xr[k] * up;
        allreduce24(A);

        // t_i = <xr, uq + A>  (local dot, 4-way ILP)
        float a0 = 0.0f, a1 = 0.0f, a2 = 0.0f, a3 = 0.0f;
        #pragma unroll
        for (int k = 0; k < 24; k += 4) {
            a0 = fmaf(xr[k + 0], uq[k + 0] + A[k + 0], a0);
            a1 = fmaf(xr[k + 1], uq[k + 1] + A[k + 1], a1);
            a2 = fmaf(xr[k + 2], uq[k + 2] + A[k + 2], a2);
            a3 = fmaf(xr[k + 3], uq[k + 3] + A[k + 3], a3);
        }
        const float ti = (a0 + a1) + (a2 + a3);

        // C = (x^T t)-slots: allreduce(xr[k] * t_i)
        float C[24];
        #pragma unroll
        for (int k = 0; k < 24; ++k) C[k] = xr[k] * ti;
        allreduce24(C);

        // updates
        up = fmaf(-2.0f, ti, up);
        #pragma unroll
        for (int k = 0; k < 24; ++k) {
            uq[k] = fmaf(2.0f, A[k], uq[k]);
            uq[k] = fmaf(-2.0f, C[k], uq[k]);
        }

        // commit prefetch
        if (t > 0) {
            #pragma unroll
            for (int u = 0; u < 6; ++u) {
                xr[4 * u + 0] = e[u].x; xr[4 * u + 1] = e[u].y;
                xr[4 * u + 2] = e[u].z; xr[4 * u + 3] = e[u].w;
            }
            if (qside) {
                #pragma unroll
                for (int k = 0; k < 24; ++k) xr[k] *= trr[k];
            }
        }
    }

    // ---- stash U (column-major). uq is bitwise-identical across the 8-group;
    // one writer (i==0) per column for the q-rows.
    Ucm[s][j][i] = up;
    if (i == 0) {
        #pragma unroll
        for (int k = 0; k < 24; ++k) Ucm[s][j][8 + k] = uq[k];
    }
    __syncthreads();

    // ---- q-side: U <- yb U  (wave-0 private: LDS reads + wave fences only)
    if (s == 0) {
        float Ucol[32];
        const float4* cu = (const float4*)&Ucm[0][j][0];
        #pragma unroll
        for (int u = 0; u < 8; ++u) {
            const float4 vv = cu[u];
            Ucol[4 * u + 0] = vv.x; Ucol[4 * u + 1] = vv.y;
            Ucol[4 * u + 2] = vv.z; Ucol[4 * u + 3] = vv.w;
        }
        float nu[4];
        #pragma unroll
        for (int c4 = 0; c4 < 4; ++c4) {
            const int r = i + 8 * c4;
            const float* yr = &ybs[r * 32];
            float acc = 0.0f;
            #pragma unroll
            for (int m = 0; m < 32; ++m) acc = fmaf(yr[m], Ucol[m], acc);
            nu[c4] = acc;
        }
        syncwave();   // all wave-0 reads of Ucm[0] complete before overwrite
        #pragma unroll
        for (int c4 = 0; c4 < 4; ++c4) Ucm[0][j][i + 8 * c4] = nu[c4];
        syncwave();

        // ---- join: dist^2 = 16 - 2 ||U0^T U1||_F^2
        const int ca = l >> 3, cb = l & 7;
        const float4* pa = (const float4*)&Ucm[0][ca][0];
        const float4* pb = (const float4*)&Ucm[1][cb][0];
        float acc = 0.0f;
        #pragma unroll
        for (int u = 0; u < 8; ++u) {
            const float4 A4 = pa[u], B4 = pb[u];
            acc += A4.x * B4.x + A4.y * B4.y + A4.z * B4.z + A4.w * B4.w;
        }
        float val = acc * acc;
        #pragma unroll
        for (int d = 1; d < 64; d <<= 1) val += __shfl_xor(val, d);
        if (l == 0) {
            const float d2 = 16.0f - 2.0f * val;
            out[b] = -wf[0] * sqrtf(fmaxf(d2, 0.0f)) + wb[0];
        }
    }
}

extern "C" void kernel_launch(void* const* d_in, const int* in_sizes, int n_in,
                              void* d_out, int out_size, void* d_ws, size_t ws_size,
                              hipStream_t stream) {
    const int* s1 = (const int*)d_in[0];
    const int* s2 = (const int*)d_in[1];
    const float* qemb  = (const float*)d_in[2];
    const float* aemb  = (const float*)d_in[3];
    const float* qtr   = (const float*)d_in[4];
    const float* qbias = (const float*)d_in[5];
    const float* wf    = (const float*)d_in[6];
    const float* wb    = (const float*)d_in[7];
    float* out = (float*)d_out;
    (void)d_ws; (void)ws_size; (void)in_sizes; (void)n_in; (void)out_size;

    chains<<<512, 128, 0, stream>>>(s1, s2, qemb, aemb, qtr, qbias, wf, wb, out);
}

// Round 6
// 120.539 us; speedup vs baseline: 1.6872x; 1.6872x over previous
//
#include <hip/hip_runtime.h>
#include <math.h>

#define TT 64

// ---- DPP add (VALU-pipe cross-lane). old=0 => masked/invalid lanes add 0.
template<int CTRL, int RM>
__device__ __forceinline__ float dppadd(float v) {
    return v + __int_as_float(__builtin_amdgcn_update_dpp(
        0, __float_as_int(v), CTRL, RM, 0xF, false));
}
// inclusive scan over the 64 lanes (classic GCN pattern)
__device__ __forceinline__ float wscan64(float v) {
    v = dppadd<0x111, 0xF>(v);   // row_shr:1
    v = dppadd<0x112, 0xF>(v);   // row_shr:2
    v = dppadd<0x114, 0xF>(v);   // row_shr:4
    v = dppadd<0x118, 0xF>(v);   // row_shr:8  -> per-16-row inclusive
    v = dppadd<0x142, 0xA>(v);   // row_bcast15 -> rows 1,3
    v = dppadd<0x143, 0xC>(v);   // row_bcast31 -> rows 2,3
    return v;
}

// ---------------------------------------------------------------------------
// prep_yb: yb = cayley(tangent_vector(question_bias)) (32x32) into ws.
// Exact 8x8 Gauss-Jordan (verified R1/R2).
// ---------------------------------------------------------------------------
__global__ __launch_bounds__(64) void prep_yb(const float* __restrict__ qbias,
                                              float* __restrict__ yb_out) {
    __shared__ float xb[8 * 24];
    __shared__ float Aug[8][16];
    __shared__ float H[8 * 24];
    const int ln = threadIdx.x;
    xb[ln] = qbias[ln];
    xb[ln + 64] = qbias[ln + 64];
    xb[ln + 128] = qbias[ln + 128];
    __syncthreads();

    const int i = ln >> 3, j = ln & 7;
    float a = (i == j) ? 1.0f : 0.0f;
    for (int k = 0; k < 24; ++k) a += xb[i * 24 + k] * xb[j * 24 + k];
    Aug[i][j] = a;
    Aug[i][j + 8] = (i == j) ? 1.0f : 0.0f;
    __syncthreads();

    for (int k = 0; k < 8; ++k) {
        const float piv = Aug[k][k];
        __syncthreads();
        if (i == k) {
            const float ip = 1.0f / piv;
            Aug[k][j] *= ip;
            Aug[k][j + 8] *= ip;
        }
        __syncthreads();
        const float f = Aug[i][k];
        __syncthreads();
        if (i != k) {
            Aug[i][j]     -= f * Aug[k][j];
            Aug[i][j + 8] -= f * Aug[k][j + 8];
        }
        __syncthreads();
    }

    for (int idx = ln; idx < 8 * 24; idx += 64) {
        const int r = idx / 24, c = idx % 24;
        float h = 0.0f;
        for (int m = 0; m < 8; ++m) h += Aug[r][8 + m] * xb[m * 24 + c];
        H[idx] = h;
    }
    __syncthreads();

    for (int idx = ln; idx < 32 * 32; idx += 64) {
        const int r = idx >> 5, c = idx & 31;
        float v;
        if (r < 8 && c < 8) {
            v = 2.0f * Aug[r][8 + c] - ((r == c) ? 1.0f : 0.0f);
        } else if (r < 8) {
            v = -2.0f * H[r * 24 + (c - 8)];
        } else if (c < 8) {
            v = 2.0f * H[c * 24 + (r - 8)];
        } else {
            float s2 = 0.0f;
            for (int m = 0; m < 8; ++m) s2 += xb[m * 24 + (r - 8)] * H[m * 24 + (c - 8)];
            v = ((r == c) ? 1.0f : 0.0f) - 2.0f * s2;
        }
        yb_out[idx] = v;
    }
}

// ---------------------------------------------------------------------------
// chains (Magnus form): block = batch; 8 waves = 2 sides x 4 row-pair waves.
// Lane = token t. Wave (side, v) owns x-rows {2v, 2v+1} (48 comps/lane).
//   Z = C_0 C_1 ... C_63 = exp(M) + O(1e-4),
//   M = [[Dp, -2S],[2S^T, 0]],  S = sum_t x_t,
//   Dp = 2(G - G^T),  G = sum_t x_t p_{t-1}^T  (p = exclusive prefix).
// Scan over t = DPP wave scan. p stored bf16 in LDS (2nd-order term).
// U = exp(M) E via 8 Taylor terms; q-side conjugated by yb;
// dist^2 = 16 - 2 ||U0^T U1||_F^2.
// ---------------------------------------------------------------------------
__global__ __launch_bounds__(512, 4) void chains(
    const int* __restrict__ s1, const int* __restrict__ s2,
    const float* __restrict__ qemb, const float* __restrict__ aemb,
    const float* __restrict__ qtr, const float* __restrict__ ybg,
    const float* __restrict__ wf, const float* __restrict__ wb,
    float* __restrict__ out) {
    __shared__ __align__(16) unsigned short Pb[2][TT][194]; // bf16 p, stride 97 dw (conflict-free)
    __shared__ float Ssm[2][8][26];
    __shared__ float Gm[2][8][8];
    __shared__ __align__(16) float VA[2][8][36];            // col-major V / U
    __shared__ __align__(16) float VB[2][8][36];
    __shared__ float ybs[32][33];

    const int tid = threadIdx.x;
    const int w  = tid >> 6;       // wave 0..7
    const int sde = w >> 2;        // side: 0=question, 1=answer
    const int v  = w & 3;          // row-pair index -> rows {2v, 2v+1}
    const int t  = tid & 63;       // token
    const int b  = blockIdx.x;

    const int* sent = sde ? s2 : s1;
    const float* emb = sde ? aemb : qemb;
    const int id = sent[b * TT + t];
    const float* xbase = emb + (size_t)id * 192 + v * 48;
    const float* trbase = qtr + v * 48;

    float x[48];

    // ---- two passes (rows 2v, 2v+1): load+scale, DPP-scan, S, pack p->LDS
    #pragma unroll
    for (int pass = 0; pass < 2; ++pass) {
        float xx[24];
        {
            const float4* xp = (const float4*)(xbase + pass * 24);
            float4 xv[6];
            #pragma unroll
            for (int u = 0; u < 6; ++u) xv[u] = xp[u];
            if (sde == 0) {
                const float4* tp = (const float4*)(trbase + pass * 24);
                #pragma unroll
                for (int u = 0; u < 6; ++u) {
                    const float4 tv = tp[u];
                    xv[u].x *= tv.x; xv[u].y *= tv.y;
                    xv[u].z *= tv.z; xv[u].w *= tv.w;
                }
            }
            #pragma unroll
            for (int u = 0; u < 6; ++u) {
                xx[4 * u + 0] = xv[u].x; xx[4 * u + 1] = xv[u].y;
                xx[4 * u + 2] = xv[u].z; xx[4 * u + 3] = xv[u].w;
            }
        }
        #pragma unroll
        for (int k = 0; k < 24; ++k) x[pass * 24 + k] = xx[k];

        float inc[24];
        #pragma unroll
        for (int k = 0; k < 24; ++k) inc[k] = wscan64(xx[k]);

        const int a = 2 * v + pass;
        if (t == 63) {   // S = inclusive total
            #pragma unroll
            for (int k = 0; k < 24; k += 2)
                *(float2*)&Ssm[sde][a][k] = make_float2(inc[k], inc[k + 1]);
        }
        // exclusive prefix, pack to bf16 pairs
        #pragma unroll
        for (int k = 0; k < 24; k += 2) {
            const float e0 = inc[k] - xx[k];
            const float e1 = inc[k + 1] - xx[k + 1];
            const unsigned d = (__float_as_uint(e0) >> 16) |
                               (__float_as_uint(e1) & 0xFFFF0000u);
            *(unsigned*)&Pb[sde][t][a * 24 + k] = d;
        }
    }

    // stage yb while waiting
    #pragma unroll
    for (int idx = tid; idx < 1024; idx += 512) ybs[idx >> 5][idx & 31] = ybg[idx];
    __syncthreads();

    // ---- G rows {2v, 2v+1}: lane-local over own t, reduce over lanes
    {
        float Ga[8], Gb[8];
        #pragma unroll
        for (int m = 0; m < 8; ++m) { Ga[m] = 0.0f; Gb[m] = 0.0f; }
        const unsigned* prow = (const unsigned*)&Pb[sde][t][0];
        #pragma unroll
        for (int bb = 0; bb < 8; ++bb) {
            #pragma unroll
            for (int d = 0; d < 12; ++d) {
                const unsigned u = prow[bb * 12 + d];
                const float p0 = __uint_as_float(u << 16);
                const float p1 = __uint_as_float(u & 0xFFFF0000u);
                Ga[bb] = fmaf(x[2 * d],      p0, Ga[bb]);
                Ga[bb] = fmaf(x[2 * d + 1],  p1, Ga[bb]);
                Gb[bb] = fmaf(x[24 + 2 * d],     p0, Gb[bb]);
                Gb[bb] = fmaf(x[24 + 2 * d + 1], p1, Gb[bb]);
            }
        }
        #pragma unroll
        for (int m = 0; m < 8; ++m) {
            #pragma unroll
            for (int d = 1; d < 64; d <<= 1) {
                Ga[m] += __shfl_xor(Ga[m], d);
                Gb[m] += __shfl_xor(Gb[m], d);
            }
        }
        if (t == 0) {
            #pragma unroll
            for (int m = 0; m < 8; ++m) {
                Gm[sde][2 * v][m]     = Ga[m];
                Gm[sde][2 * v + 1][m] = Gb[m];
            }
        }
    }
    __syncthreads();

    // ---- U = exp(M) E, thread-per-entry: (sd2, r, c)
    const int sd2 = tid >> 8;      // side for epilogue (renamed: param s2 is a pointer)
    const int e  = tid & 255;
    const int c  = e & 7;
    const int r  = e >> 3;

    float mrow[32];
    if (r < 8) {
        #pragma unroll
        for (int m = 0; m < 8; ++m) mrow[m] = 2.0f * (Gm[sd2][r][m] - Gm[sd2][m][r]);
        #pragma unroll
        for (int k = 0; k < 24; ++k) mrow[8 + k] = -2.0f * Ssm[sd2][r][k];
    } else {
        #pragma unroll
        for (int m = 0; m < 8; ++m) mrow[m] = 2.0f * Ssm[sd2][m][r - 8];
        #pragma unroll
        for (int k = 0; k < 24; ++k) mrow[8 + k] = 0.0f;
    }

    float acc = (r == c) ? 1.0f : 0.0f;
    VA[sd2][c][r] = acc;
    __syncthreads();

    const float invn[8] = {1.0f, 0.5f, 1.0f / 3.0f, 0.25f,
                           0.2f, 1.0f / 6.0f, 1.0f / 7.0f, 0.125f};
    #pragma unroll
    for (int n = 0; n < 8; ++n) {
        const float* rd = (n & 1) ? &VB[sd2][c][0] : &VA[sd2][c][0];
        float dot = 0.0f;
        if (r < 8) {
            #pragma unroll
            for (int m = 0; m < 32; ++m) dot = fmaf(mrow[m], rd[m], dot);
        } else {
            #pragma unroll
            for (int m = 0; m < 8; ++m) dot = fmaf(mrow[m], rd[m], dot);
        }
        const float nv = dot * invn[n];
        acc += nv;
        float* wr = (n & 1) ? &VA[sd2][c][0] : &VB[sd2][c][0];
        wr[r] = nv;
        __syncthreads();
    }

    // U_raw -> VB; q-side conjugate by yb -> VA; a-side copy
    VB[sd2][c][r] = acc;
    __syncthreads();
    float fin;
    if (sd2 == 0) {
        const float* ucol = &VB[0][c][0];
        float a2 = 0.0f;
        #pragma unroll
        for (int m = 0; m < 32; ++m) a2 = fmaf(ybs[r][m], ucol[m], a2);
        fin = a2;
    } else {
        fin = acc;
    }
    VA[sd2][c][r] = fin;
    __syncthreads();

    // ---- join on wave 0: dist^2 = 16 - 2 ||U0^T U1||_F^2
    if (w == 0) {
        const int a = t >> 3, bb2 = t & 7;
        const float* ca = &VA[0][a][0];
        const float* cb = &VA[1][bb2][0];
        float dot = 0.0f;
        #pragma unroll
        for (int m = 0; m < 32; ++m) dot = fmaf(ca[m], cb[m], dot);
        float val = dot * dot;
        #pragma unroll
        for (int d = 1; d < 64; d <<= 1) val += __shfl_xor(val, d);
        if (t == 0) {
            const float d2 = 16.0f - 2.0f * val;
            out[b] = -wf[0] * sqrtf(fmaxf(d2, 0.0f)) + wb[0];
        }
    }
}

extern "C" void kernel_launch(void* const* d_in, const int* in_sizes, int n_in,
                              void* d_out, int out_size, void* d_ws, size_t ws_size,
                              hipStream_t stream) {
    const int* s1 = (const int*)d_in[0];
    const int* s2 = (const int*)d_in[1];
    const float* qemb  = (const float*)d_in[2];
    const float* aemb  = (const float*)d_in[3];
    const float* qtr   = (const float*)d_in[4];
    const float* qbias = (const float*)d_in[5];
    const float* wf    = (const float*)d_in[6];
    const float* wb    = (const float*)d_in[7];
    float* out = (float*)d_out;
    float* yb = (float*)d_ws;   // 1024 floats

    prep_yb<<<1, 64, 0, stream>>>(qbias, yb);
    chains<<<512, 512, 0, stream>>>(s1, s2, qemb, aemb, qtr, yb, wf, wb, out);
}

// Round 7
// 113.895 us; speedup vs baseline: 1.7857x; 1.0583x over previous
//
#include <hip/hip_runtime.h>
#include <math.h>

#define TT 64

// wave-local LDS fence: waitcnt lgkmcnt(0) only (vmcnt untouched).
__device__ __forceinline__ void syncwave() {
    __builtin_amdgcn_wave_barrier();
    __builtin_amdgcn_s_waitcnt(0xC07F);   // vmcnt=63(no wait), expcnt=7, lgkmcnt=0
    __builtin_amdgcn_wave_barrier();
}

// ---- DPP add (VALU-pipe cross-lane). old=0, bound_ctrl=false.
template<int CTRL, int RM>
__device__ __forceinline__ float dppadd(float v) {
    return v + __int_as_float(__builtin_amdgcn_update_dpp(
        0, __float_as_int(v), CTRL, RM, 0xF, false));
}
// inclusive scan over 64 lanes (verified R6: absmax matched Magnus-only error)
__device__ __forceinline__ float wscan64(float v) {
    v = dppadd<0x111, 0xF>(v);   // row_shr:1
    v = dppadd<0x112, 0xF>(v);   // row_shr:2
    v = dppadd<0x114, 0xF>(v);   // row_shr:4
    v = dppadd<0x118, 0xF>(v);   // row_shr:8
    v = dppadd<0x142, 0xA>(v);   // row_bcast15 -> rows 1,3
    v = dppadd<0x143, 0xC>(v);   // row_bcast31 -> rows 2,3
    return v;
}
// rotation allreduce within each 16-lane row (any fixed rotations 1,2,4,8 sum all 16)
__device__ __forceinline__ float rowsum16(float v) {
    v = dppadd<0x121, 0xF>(v);   // row_ror:1
    v = dppadd<0x122, 0xF>(v);   // row_ror:2
    v = dppadd<0x124, 0xF>(v);   // row_ror:4
    v = dppadd<0x128, 0xF>(v);   // row_ror:8
    return v;
}

// ---------------------------------------------------------------------------
// chains (Magnus form, single kernel): block = batch; 8 waves = 2 sides x 4
// row-pair waves; lane = token t. Wave (side,v) owns x-rows {2v,2v+1}.
//   Z ~ exp(M), M = [[Dp, -2S],[2S^T, 0]], S = sum_t x_t,
//   Dp = 2(G - G^T), G = sum_t x_t p_{t-1}^T (p = exclusive prefix, bf16 LDS).
// Wave 0 additionally builds yb = cayley(bias) via exact Gauss-Jordan (R3-
// verified wave-sync pattern). U = exp(M)E via 6 Taylor terms, wave-local.
// dist^2 = 16 - 2||U0^T U1||_F^2. 4 block barriers total.
// ---------------------------------------------------------------------------
__global__ __launch_bounds__(512, 4) void chains(
    const int* __restrict__ s1, const int* __restrict__ s2,
    const float* __restrict__ qemb, const float* __restrict__ aemb,
    const float* __restrict__ qtr, const float* __restrict__ qbias,
    const float* __restrict__ wf, const float* __restrict__ wb,
    float* __restrict__ out) {
    // p storage: bf16 pairs, 96 data dwords + pad -> stride 100 dwords
    // (16B-aligned; bank starts 4t mod 32 -> optimal 8-cycle b128 access)
    __shared__ __align__(16) unsigned Pb[2][TT][100];     // 51200 B
    __shared__ float Ssm[2 * 8 * 28];                     // 1792 B (row stride 112B, 16B-mult)
    __shared__ float Gm[2][8][8];                         // 512 B
    __shared__ float ybs[32 * 36];                        // 4608 B (row 144B, 16B-mult)
    __shared__ float Tb[8 * 2 * 36];                      // 2304 B
    __shared__ float Ufin[2 * 8 * 36];                    // 2304 B
    // union: Gauss-Jordan scratch (pre-barrier-A) / Gpart (post-barrier-A)
    __shared__ __align__(16) float scr[512];              // 2048 B  -> total 64768 B

    float* xbp  = scr;          // [192]
    float* Augp = scr + 192;    // [8*16]
    float* Hmp  = scr + 320;    // [192]
    float* Gpart = scr;         // [2][4][4][16] flat: ((side*4+v)*4+g)*16+m

    const int tid = threadIdx.x;
    const int w   = tid >> 6;        // wave 0..7
    const int sde = w >> 2;          // side 0=q, 1=a
    const int v   = w & 3;           // row pair {2v, 2v+1}
    const int t   = tid & 63;        // token
    const int b   = blockIdx.x;

    // wave 0 preloads bias early (consumed in GJ below)
    float qb0 = 0.f, qb1 = 0.f, qb2 = 0.f;
    if (w == 0) { qb0 = qbias[t]; qb1 = qbias[t + 64]; qb2 = qbias[t + 128]; }

    const int* sent = sde ? s2 : s1;
    const float* emb = sde ? aemb : qemb;
    const int id = sent[b * TT + t];
    const float* xbase  = emb + (size_t)id * 192 + v * 48;
    const float* trbase = qtr + v * 48;

    float x[48];

    // ---- scan + pack (two passes: rows 2v, 2v+1)
    #pragma unroll
    for (int pass = 0; pass < 2; ++pass) {
        {
            const float4* xp = (const float4*)(xbase + pass * 24);
            float4 xv[6];
            #pragma unroll
            for (int u = 0; u < 6; ++u) xv[u] = xp[u];
            if (sde == 0) {
                const float4* tp = (const float4*)(trbase + pass * 24);
                #pragma unroll
                for (int u = 0; u < 6; ++u) {
                    const float4 tv = tp[u];
                    xv[u].x *= tv.x; xv[u].y *= tv.y;
                    xv[u].z *= tv.z; xv[u].w *= tv.w;
                }
            }
            #pragma unroll
            for (int u = 0; u < 6; ++u) {
                x[pass * 24 + 4 * u + 0] = xv[u].x;
                x[pass * 24 + 4 * u + 1] = xv[u].y;
                x[pass * 24 + 4 * u + 2] = xv[u].z;
                x[pass * 24 + 4 * u + 3] = xv[u].w;
            }
        }
        float inc[24];
        #pragma unroll
        for (int k = 0; k < 24; ++k) inc[k] = wscan64(x[pass * 24 + k]);

        const int a = 2 * v + pass;
        if (t == 63) {   // S totals
            float4* sp = (float4*)&Ssm[(sde * 8 + a) * 28];
            sp[0] = make_float4(inc[0], inc[1], inc[2], inc[3]);
            sp[1] = make_float4(inc[4], inc[5], inc[6], inc[7]);
            sp[2] = make_float4(inc[8], inc[9], inc[10], inc[11]);
            sp[3] = make_float4(inc[12], inc[13], inc[14], inc[15]);
            sp[4] = make_float4(inc[16], inc[17], inc[18], inc[19]);
            sp[5] = make_float4(inc[20], inc[21], inc[22], inc[23]);
        }
        unsigned pk[12];
        #pragma unroll
        for (int k = 0; k < 24; k += 2) {
            const float e0 = inc[k] - x[pass * 24 + k];
            const float e1 = inc[k + 1] - x[pass * 24 + k + 1];
            pk[k >> 1] = (__float_as_uint(e0) >> 16) |
                         (__float_as_uint(e1) & 0xFFFF0000u);
        }
        uint4* dst = (uint4*)&Pb[sde][t][a * 12];
        dst[0] = make_uint4(pk[0], pk[1], pk[2], pk[3]);
        dst[1] = make_uint4(pk[4], pk[5], pk[6], pk[7]);
        dst[2] = make_uint4(pk[8], pk[9], pk[10], pk[11]);
    }

    // ---- wave 0: yb = cayley(bias) via exact Gauss-Jordan (wave-sync, R3-verified)
    if (w == 0) {
        xbp[t] = qb0; xbp[t + 64] = qb1; xbp[t + 128] = qb2;
        syncwave();
        const int gi = t >> 3, gj = t & 7;
        float a = (gi == gj) ? 1.0f : 0.0f;
        for (int k = 0; k < 24; ++k) a += xbp[gi * 24 + k] * xbp[gj * 24 + k];
        Augp[gi * 16 + gj] = a;
        Augp[gi * 16 + gj + 8] = (gi == gj) ? 1.0f : 0.0f;
        syncwave();
        for (int k = 0; k < 8; ++k) {
            const float piv = Augp[k * 16 + k];
            syncwave();
            if (gi == k) {
                const float ip = 1.0f / piv;
                Augp[k * 16 + gj] *= ip;
                Augp[k * 16 + gj + 8] *= ip;
            }
            syncwave();
            const float f = Augp[gi * 16 + k];
            syncwave();
            if (gi != k) {
                Augp[gi * 16 + gj]     -= f * Augp[k * 16 + gj];
                Augp[gi * 16 + gj + 8] -= f * Augp[k * 16 + gj + 8];
            }
            syncwave();
        }
        for (int idx = t; idx < 192; idx += 64) {
            const int r = idx / 24, c = idx % 24;
            float h = 0.0f;
            for (int m = 0; m < 8; ++m) h += Augp[r * 16 + 8 + m] * xbp[m * 24 + c];
            Hmp[idx] = h;
        }
        syncwave();
        for (int idx = t; idx < 1024; idx += 64) {
            const int r = idx >> 5, c = idx & 31;
            float vv;
            if (r < 8 && c < 8) {
                vv = 2.0f * Augp[r * 16 + 8 + c] - ((r == c) ? 1.0f : 0.0f);
            } else if (r < 8) {
                vv = -2.0f * Hmp[r * 24 + (c - 8)];
            } else if (c < 8) {
                vv = 2.0f * Hmp[c * 24 + (r - 8)];
            } else {
                float s2v = 0.0f;
                for (int m = 0; m < 8; ++m)
                    s2v += xbp[m * 24 + (r - 8)] * Hmp[m * 24 + (c - 8)];
                vv = ((r == c) ? 1.0f : 0.0f) - 2.0f * s2v;
            }
            ybs[r * 36 + c] = vv;
        }
    }
    __syncthreads();   // A: Pb, Ssm, ybs ready; GJ scratch dead

    // ---- G MACs: rows {2v,2v+1} x all 8 p-rows, inner dim 24 (bf16 unpack)
    float Ga[8], Gb[8];
    #pragma unroll
    for (int m = 0; m < 8; ++m) { Ga[m] = 0.0f; Gb[m] = 0.0f; }
    #pragma unroll
    for (int b8 = 0; b8 < 8; ++b8) {
        const uint4* pv = (const uint4*)&Pb[sde][t][b8 * 12];
        const uint4 qa = pv[0], qb = pv[1], qc = pv[2];
        const unsigned ww[12] = {qa.x, qa.y, qa.z, qa.w,
                                 qb.x, qb.y, qb.z, qb.w,
                                 qc.x, qc.y, qc.z, qc.w};
        #pragma unroll
        for (int d = 0; d < 12; ++d) {
            const float p0 = __uint_as_float(ww[d] << 16);
            const float p1 = __uint_as_float(ww[d] & 0xFFFF0000u);
            Ga[b8] = fmaf(x[2 * d],          p0, Ga[b8]);
            Ga[b8] = fmaf(x[2 * d + 1],      p1, Ga[b8]);
            Gb[b8] = fmaf(x[24 + 2 * d],     p0, Gb[b8]);
            Gb[b8] = fmaf(x[24 + 2 * d + 1], p1, Gb[b8]);
        }
    }
    // rotation allreduce within 16-lane groups (VALU pipe), 4 partials per entry
    #pragma unroll
    for (int m = 0; m < 8; ++m) { Ga[m] = rowsum16(Ga[m]); Gb[m] = rowsum16(Gb[m]); }
    if ((t & 15) == 0) {
        const int g = t >> 4;
        float4* gp = (float4*)&Gpart[((sde * 4 + v) * 4 + g) * 16];
        gp[0] = make_float4(Ga[0], Ga[1], Ga[2], Ga[3]);
        gp[1] = make_float4(Ga[4], Ga[5], Ga[6], Ga[7]);
        gp[2] = make_float4(Gb[0], Gb[1], Gb[2], Gb[3]);
        gp[3] = make_float4(Gb[4], Gb[5], Gb[6], Gb[7]);
    }
    __syncthreads();   // B

    if (tid < 128) {   // assemble G: entry (side, a, bb)
        const int side = tid >> 6, rem = tid & 63;
        const int a = rem >> 3, bb = rem & 7;
        const int vv = a >> 1, m = (a & 1) * 8 + bb;
        const int base = (side * 4 + vv) * 4 * 16 + m;
        const float g = Gpart[base] + Gpart[base + 16] +
                        Gpart[base + 32] + Gpart[base + 48];
        Gm[side][a][bb] = g;
    }
    __syncthreads();   // C

    // ---- epilogue: U = exp(M)E, column c in 32 lanes of one wave (wave-local)
    const int cc = t >> 5;                 // column-within-wave
    const int r  = t & 31;                 // row
    const int c  = 2 * (w & 3) + cc;       // column 0..7
    float mrow[32];
    if (r < 8) {
        #pragma unroll
        for (int m = 0; m < 8; ++m) mrow[m] = 2.0f * (Gm[sde][r][m] - Gm[sde][m][r]);
        const float4* sp = (const float4*)&Ssm[(sde * 8 + r) * 28];
        #pragma unroll
        for (int u6 = 0; u6 < 6; ++u6) {
            const float4 q = sp[u6];
            mrow[8 + 4 * u6 + 0] = -2.0f * q.x;
            mrow[8 + 4 * u6 + 1] = -2.0f * q.y;
            mrow[8 + 4 * u6 + 2] = -2.0f * q.z;
            mrow[8 + 4 * u6 + 3] = -2.0f * q.w;
        }
    } else {
        #pragma unroll
        for (int m = 0; m < 8; ++m) mrow[m] = 2.0f * Ssm[(sde * 8 + m) * 28 + (r - 8)];
        #pragma unroll
        for (int k = 8; k < 32; ++k) mrow[k] = 0.0f;
    }

    float uacc = (r == c) ? 1.0f : 0.0f;
    float term = uacc;
    const float invn[6] = {1.0f, 0.5f, 1.0f / 3.0f, 0.25f, 0.2f, 1.0f / 6.0f};
    float* tb = &Tb[(w * 2 + cc) * 36];
    #pragma unroll
    for (int n = 0; n < 6; ++n) {
        tb[r] = term;
        syncwave();
        const float4* tv = (const float4*)tb;
        float dot = 0.0f;
        #pragma unroll
        for (int u8 = 0; u8 < 8; ++u8) {
            const float4 q = tv[u8];
            dot = fmaf(mrow[4 * u8 + 0], q.x, dot);
            dot = fmaf(mrow[4 * u8 + 1], q.y, dot);
            dot = fmaf(mrow[4 * u8 + 2], q.z, dot);
            dot = fmaf(mrow[4 * u8 + 3], q.w, dot);
        }
        term = dot * invn[n];
        uacc += term;
        syncwave();   // WAR: all reads done before next iter's write
    }
    if (sde == 0) {   // q-side: U <- yb U
        tb[r] = uacc;
        syncwave();
        const float4* tv = (const float4*)tb;
        const float4* yr = (const float4*)&ybs[r * 36];
        float dot = 0.0f;
        #pragma unroll
        for (int u8 = 0; u8 < 8; ++u8) {
            const float4 q = tv[u8], y = yr[u8];
            dot = fmaf(y.x, q.x, dot); dot = fmaf(y.y, q.y, dot);
            dot = fmaf(y.z, q.z, dot); dot = fmaf(y.w, q.w, dot);
        }
        uacc = dot;
    }
    Ufin[(sde * 8 + c) * 36 + r] = uacc;
    __syncthreads();   // D

    // ---- join on wave 0: dist^2 = 16 - 2 ||U0^T U1||_F^2
    if (w == 0) {
        const int a = t >> 3, b2 = t & 7;
        const float4* pa = (const float4*)&Ufin[a * 36];
        const float4* pb = (const float4*)&Ufin[(8 + b2) * 36];
        float dot = 0.0f;
        #pragma unroll
        for (int u8 = 0; u8 < 8; ++u8) {
            const float4 A4 = pa[u8], B4 = pb[u8];
            dot = fmaf(A4.x, B4.x, dot); dot = fmaf(A4.y, B4.y, dot);
            dot = fmaf(A4.z, B4.z, dot); dot = fmaf(A4.w, B4.w, dot);
        }
        float val = dot * dot;
        #pragma unroll
        for (int d = 1; d < 64; d <<= 1) val += __shfl_xor(val, d);
        if (t == 0) {
            const float d2 = 16.0f - 2.0f * val;
            out[b] = -wf[0] * sqrtf(fmaxf(d2, 0.0f)) + wb[0];
        }
    }
}

extern "C" void kernel_launch(void* const* d_in, const int* in_sizes, int n_in,
                              void* d_out, int out_size, void* d_ws, size_t ws_size,
                              hipStream_t stream) {
    const int* s1 = (const int*)d_in[0];
    const int* s2 = (const int*)d_in[1];
    const float* qemb  = (const float*)d_in[2];
    const float* aemb  = (const float*)d_in[3];
    const float* qtr   = (const float*)d_in[4];
    const float* qbias = (const float*)d_in[5];
    const float* wf    = (const float*)d_in[6];
    const float* wb    = (const float*)d_in[7];
    float* out = (float*)d_out;
    (void)d_ws; (void)ws_size; (void)in_sizes; (void)n_in; (void)out_size;

    chains<<<512, 512, 0, stream>>>(s1, s2, qemb, aemb, qtr, qbias, wf, wb, out);
}